// Round 5
// baseline (217.304 us; speedup 1.0000x reference)
//
#include <hip/hip_runtime.h>

#define PNUM 128
#define BATCH 8192
#define WPB 2                      // waves per block, 1 batch per wave
#define GRID1 (BATCH / WPB)        // 4096 blocks of 128 threads

// smooth-L1 accumulate, 4 VALU (abs/min via modifiers):
// m = min(|d|,1); acc += m*(|d| - 0.5m)
__device__ __forceinline__ float term(float p, float q, float acc) {
    float d = p - q;
    float a = fabsf(d);
    float m = fminf(a, 1.0f);
    float t = fmaf(-0.5f, m, a);
    return fmaf(m, t, acc);
}

// One WAVE per batch, both preds. Lane k owns shifts {2k,2k+1}.
// ALL loop operands come from per-wave LDS (single in-order lgkmcnt pipe):
//  - gt ring doubled -> sliding float4 window, 1 consecutive-block b128/iter
//  - pred rows -> wave-uniform broadcast b128 reads (conflict-free)
// No __syncthreads in the main path (per-wave LDS regions only).
// Final reduction fused via device-scope atomic last-block-done.
__global__ __launch_bounds__(64 * WPB, 8) void match_fused(
        const float* __restrict__ pred0,
        const float* __restrict__ pred1,
        const float* __restrict__ gt,
        unsigned* __restrict__ counter,    // ws[0]
        float* __restrict__ sums,          // ws + 16 floats, GRID1 entries
        float* __restrict__ out) {
    __shared__ float4 sg [WPB][2 * PNUM / 2];  // doubled gt ring, 2 KB/wave
    __shared__ float4 sp0[WPB][PNUM / 2];      // pred0 row, 1 KB/wave
    __shared__ float4 sp1[WPB][PNUM / 2];      // pred1 row, 1 KB/wave

    const int t = threadIdx.x;
    const int k = t & 63;
    const int w = __builtin_amdgcn_readfirstlane(t >> 6);
    const int b = blockIdx.x * WPB + w;

    // ---- stage all three rows into this wave's LDS (no barrier needed) ----
    const float4* gv4 = (const float4*)(gt    + (size_t)b * (PNUM * 2));
    const float4* p0v = (const float4*)(pred0 + (size_t)b * (PNUM * 2));
    const float4* p1v = (const float4*)(pred1 + (size_t)b * (PNUM * 2));
    float4 gA = gv4[k];
    sg[w][k]      = gA;
    sg[w][k + 64] = gA;
    sp0[w][k] = p0v[k];
    sp1[w][k] = p1v[k];

    const float4* gw4 = sg[w];
    const float4* q0  = sp0[w];
    const float4* q1  = sp1[w];

    float4 w01 = gw4[k];               // {ring[2k], ring[2k+1]}
    float a0p0 = 0.f, a1p0 = 0.f, a0p1 = 0.f, a1p1 = 0.f;

#pragma unroll 8
    for (int h = 0; h < PNUM / 2; ++h) {
        float4 n01 = gw4[k + h + 1];   // lane-consecutive blocks: conflict-benign
        float4 P0  = q0[h];            // wave-uniform addr -> broadcast
        float4 P1  = q1[h];

        // shift 2k : p[2h] vs w01.xy, p[2h+1] vs w01.zw
        a0p0 = term(P0.x, w01.x, a0p0); a0p0 = term(P0.y, w01.y, a0p0);
        a0p0 = term(P0.z, w01.z, a0p0); a0p0 = term(P0.w, w01.w, a0p0);
        a0p1 = term(P1.x, w01.x, a0p1); a0p1 = term(P1.y, w01.y, a0p1);
        a0p1 = term(P1.z, w01.z, a0p1); a0p1 = term(P1.w, w01.w, a0p1);
        // shift 2k+1 : p[2h] vs w01.zw, p[2h+1] vs n01.xy
        a1p0 = term(P0.x, w01.z, a1p0); a1p0 = term(P0.y, w01.w, a1p0);
        a1p0 = term(P0.z, n01.x, a1p0); a1p0 = term(P0.w, n01.y, a1p0);
        a1p1 = term(P1.x, w01.z, a1p1); a1p1 = term(P1.y, w01.w, a1p1);
        a1p1 = term(P1.z, n01.x, a1p1); a1p1 = term(P1.w, n01.y, a1p1);

        w01 = n01;
    }

    // per-pred min over lane's 2 shifts, then over the wave; sum the two mins
    float r0 = fminf(a0p0, a1p0);
    float r1 = fminf(a0p1, a1p1);
#pragma unroll
    for (int m = 32; m > 0; m >>= 1) {
        r0 = fminf(r0, __shfl_xor(r0, m, 64));
        r1 = fminf(r1, __shfl_xor(r1, m, 64));
    }

    // ---- block sum -> global; last block reduces all block sums ----
    __shared__ float bsum[WPB];
    __shared__ int isLast;
    if (k == 0) bsum[w] = r0 + r1;
    __syncthreads();
    if (t == 0) {
        sums[blockIdx.x] = bsum[0] + bsum[1];
        __threadfence();                       // release block sum
        unsigned old = atomicAdd(counter, 1u); // device-scope
        isLast = (old == GRID1 - 1);
    }
    __syncthreads();
    if (isLast) {
        __threadfence();                       // acquire all block sums
        float s = 0.f;
#pragma unroll
        for (int q = 0; q < GRID1 / 128; ++q)  // 32 loads per thread
            s += sums[t + q * 128];
#pragma unroll
        for (int m = 32; m > 0; m >>= 1) s += __shfl_xor(s, m, 64);
        __shared__ float wsum[WPB];
        if (k == 0) wsum[w] = s;
        __syncthreads();
        if (t == 0) {
            // mean over j (1/PNUM), mean over batch (1/BATCH), avg of 2 preds
            out[0] = (wsum[0] + wsum[1]) * (1.0f / (2.0f * BATCH * PNUM));
        }
    }
}

extern "C" void kernel_launch(void* const* d_in, const int* in_sizes, int n_in,
                              void* d_out, int out_size, void* d_ws, size_t ws_size,
                              hipStream_t stream) {
    const float* pred0 = (const float*)d_in[0];
    const float* pred1 = (const float*)d_in[1];
    const float* gt    = (const float*)d_in[2];
    float* out = (float*)d_out;
    unsigned* counter = (unsigned*)d_ws;
    float* sums = (float*)d_ws + 16;           // cacheline-separated from counter

    hipMemsetAsync(d_ws, 0, 64, stream);       // zero the arrival counter
    match_fused<<<GRID1, 64 * WPB, 0, stream>>>(pred0, pred1, gt,
                                                counter, sums, out);
}

// Round 6
// 134.130 us; speedup vs baseline: 1.6201x; 1.6201x over previous
//
#include <hip/hip_runtime.h>

#define PNUM 128
#define BATCH 8192
#define NPAIR (2 * BATCH)
#define WPB 4                      // waves per block, 1 batch per wave
#define GRID1 (BATCH / WPB)        // 2048 blocks of 256 threads

// smooth-L1 accumulate, 4 VALU (abs/min via modifiers):
// m = min(|d|,1); acc += m*(|d| - 0.5m)
__device__ __forceinline__ float term(float p, float q, float acc) {
    float d = p - q;
    float a = fabsf(d);
    float m = fminf(a, 1.0f);
    float t = fmaf(-0.5f, m, a);
    return fmaf(m, t, acc);
}

// One WAVE per batch, both preds. Lane k owns shifts {2k,2k+1}.
// ALL loop operands come from per-wave LDS (single in-order lgkmcnt pipe):
//  - gt ring doubled -> sliding float4 window, 1 lane-consecutive b128 / 2 j
//  - pred rows -> wave-uniform broadcast b128 reads (conflict-free)
// No __syncthreads in the main path (per-wave LDS regions only).
__global__ __launch_bounds__(64 * WPB, 8) void match_stage1(
        const float* __restrict__ pred0,
        const float* __restrict__ pred1,
        const float* __restrict__ gt,
        float* __restrict__ ws) {
    __shared__ float4 sg [WPB][2 * PNUM / 2];  // doubled gt ring, 2 KB/wave
    __shared__ float4 sp0[WPB][PNUM / 2];      // pred0 row, 1 KB/wave
    __shared__ float4 sp1[WPB][PNUM / 2];      // pred1 row, 1 KB/wave

    const int t = threadIdx.x;
    const int k = t & 63;
    const int w = __builtin_amdgcn_readfirstlane(t >> 6);
    const int b = blockIdx.x * WPB + w;

    // ---- stage all three rows into this wave's LDS (no barrier needed) ----
    const float4* gv4 = (const float4*)(gt    + (size_t)b * (PNUM * 2));
    const float4* p0v = (const float4*)(pred0 + (size_t)b * (PNUM * 2));
    const float4* p1v = (const float4*)(pred1 + (size_t)b * (PNUM * 2));
    float4 gA = gv4[k];
    sg[w][k]      = gA;
    sg[w][k + 64] = gA;
    sp0[w][k] = p0v[k];
    sp1[w][k] = p1v[k];

    const float4* gw4 = sg[w];
    const float4* q0  = sp0[w];
    const float4* q1  = sp1[w];

    float4 w01 = gw4[k];               // {ring[2k], ring[2k+1]}
    float a0p0 = 0.f, a1p0 = 0.f, a0p1 = 0.f, a1p1 = 0.f;

#pragma unroll 8
    for (int h = 0; h < PNUM / 2; ++h) {
        float4 n01 = gw4[k + h + 1];   // lane-consecutive blocks
        float4 P0  = q0[h];            // wave-uniform addr -> broadcast
        float4 P1  = q1[h];

        // shift 2k : p[2h] vs w01.xy, p[2h+1] vs w01.zw
        a0p0 = term(P0.x, w01.x, a0p0); a0p0 = term(P0.y, w01.y, a0p0);
        a0p0 = term(P0.z, w01.z, a0p0); a0p0 = term(P0.w, w01.w, a0p0);
        a0p1 = term(P1.x, w01.x, a0p1); a0p1 = term(P1.y, w01.y, a0p1);
        a0p1 = term(P1.z, w01.z, a0p1); a0p1 = term(P1.w, w01.w, a0p1);
        // shift 2k+1 : p[2h] vs w01.zw, p[2h+1] vs n01.xy
        a1p0 = term(P0.x, w01.z, a1p0); a1p0 = term(P0.y, w01.w, a1p0);
        a1p0 = term(P0.z, n01.x, a1p0); a1p0 = term(P0.w, n01.y, a1p0);
        a1p1 = term(P1.x, w01.z, a1p1); a1p1 = term(P1.y, w01.w, a1p1);
        a1p1 = term(P1.z, n01.x, a1p1); a1p1 = term(P1.w, n01.y, a1p1);

        w01 = n01;
    }

    // per-pred min over lane's 2 shifts, then over the wave
    float r0 = fminf(a0p0, a1p0);
    float r1 = fminf(a0p1, a1p1);
#pragma unroll
    for (int m = 32; m > 0; m >>= 1) {
        r0 = fminf(r0, __shfl_xor(r0, m, 64));
        r1 = fminf(r1, __shfl_xor(r1, m, 64));
    }
    if (k == 0) {
        ws[2 * b]     = r0;
        ws[2 * b + 1] = r1;
    }
}

// Sum 16384 per-pair mins -> scalar. float4 loads, 4 independent per thread.
__global__ __launch_bounds__(1024) void match_stage2(
        const float* __restrict__ ws, float* __restrict__ out) {
    const int t = threadIdx.x;
    const float4* ws4 = (const float4*)ws;      // 4096 float4
    float s = 0.f;
#pragma unroll
    for (int q = 0; q < 4; ++q) {
        float4 v = ws4[t + q * 1024];
        s += (v.x + v.y) + (v.z + v.w);
    }
#pragma unroll
    for (int m = 32; m > 0; m >>= 1) s += __shfl_xor(s, m, 64);

    __shared__ float wsum[16];
    if ((t & 63) == 0) wsum[t >> 6] = s;
    __syncthreads();
    if (t == 0) {
        float tot = 0.f;
#pragma unroll
        for (int i = 0; i < 16; ++i) tot += wsum[i];
        // mean over j (1/PNUM), mean over batch (1/BATCH), avg of two preds (1/2)
        out[0] = tot * (1.0f / (2.0f * BATCH * PNUM));
    }
}

extern "C" void kernel_launch(void* const* d_in, const int* in_sizes, int n_in,
                              void* d_out, int out_size, void* d_ws, size_t ws_size,
                              hipStream_t stream) {
    const float* pred0 = (const float*)d_in[0];
    const float* pred1 = (const float*)d_in[1];
    const float* gt    = (const float*)d_in[2];
    float* out = (float*)d_out;
    float* ws  = (float*)d_ws;   // NPAIR floats = 64 KiB

    match_stage1<<<GRID1, 64 * WPB, 0, stream>>>(pred0, pred1, gt, ws);
    match_stage2<<<1, 1024, 0, stream>>>(ws, out);
}

// Round 8
// 113.349 us; speedup vs baseline: 1.9171x; 1.1833x over previous
//
#include <hip/hip_runtime.h>

#define PNUM 128
#define BATCH 8192
#define WPB 4                      // waves per block, 1 batch per wave
#define GRID1 (BATCH / WPB)        // 2048 blocks of 256 threads

typedef _Float16 h2 __attribute__((ext_vector_type(2)));
typedef _Float16 h4 __attribute__((ext_vector_type(4)));
typedef _Float16 h8 __attribute__((ext_vector_type(8)));

// f32x2 -> f16x2 (RTZ), bit-cast around clang's __fp16/_Float16 vec mismatch
__device__ __forceinline__ h2 cvt2(float x, float y) {
    return __builtin_bit_cast(h2, __builtin_amdgcn_cvt_pkrtz(x, y));
}

// One packed smooth-L1 term over both coords of a point pair, f32-accumulated:
// d=p-q, a=|d|, m=min(a,1), t=a-0.5m, acc=dot2(m,t)+acc. ~5 VALU / point-pair.
__device__ __forceinline__ void unit(h2 p, h2 q, float& acc) {
    h2 d = p - q;
    h2 a = __builtin_elementwise_abs(d);
    h2 m = __builtin_elementwise_min(a, (h2)(_Float16)1.0f);
    h2 t = a - m * (h2)(_Float16)0.5f;
#if __has_builtin(__builtin_amdgcn_fdot2)
    acc = __builtin_amdgcn_fdot2(m, t, acc, false);
#else
    acc += (float)m.x * (float)t.x + (float)m.y * (float)t.y;
#endif
}

__device__ __forceinline__ h2 lo2(h4 v) { return __builtin_shufflevector(v, v, 0, 1); }
__device__ __forceinline__ h2 hi2(h4 v) { return __builtin_shufflevector(v, v, 2, 3); }

// One WAVE per batch, both preds. Lane k owns shifts {2k,2k+1}.
// gt ring (doubled, f16-converted) + pred rows in per-wave LDS.
// Per hh: 4 j handled; 2x ds_read_b64 lane-sliding gather + 2x b128 broadcast.
// Fused finish: one relaxed atomicAdd per block (no fence -> no L2 writeback).
__global__ __launch_bounds__(64 * WPB, 6) void match_fused(
        const float* __restrict__ pred0,
        const float* __restrict__ pred1,
        const float* __restrict__ gt,
        float* __restrict__ out) {
    __shared__ __align__(16) _Float16 lds[WPB][1024];  // ring 512 | p0 256 | p1 256

    const int t = threadIdx.x;
    const int k = t & 63;
    const int w = __builtin_amdgcn_readfirstlane(t >> 6);
    const int b = blockIdx.x * WPB + w;

    _Float16* base = lds[w];
    h4* ring4 = (h4*)base;               // 128 entries = 256 points (doubled)
    h4* q0 = (h4*)(base + 512);          // 64 entries = 128 points
    h4* q1 = (h4*)(base + 768);

    // ---- stage + f32->f16 convert (own wave's region; no barrier needed) ----
    const float4* gv4 = (const float4*)(gt    + (size_t)b * (PNUM * 2));
    const float4* p0v = (const float4*)(pred0 + (size_t)b * (PNUM * 2));
    const float4* p1v = (const float4*)(pred1 + (size_t)b * (PNUM * 2));
    {
        float4 g = gv4[k];
        h2 c0 = cvt2(g.x, g.y);
        h2 c1 = cvt2(g.z, g.w);
        h4 gh = {c0.x, c0.y, c1.x, c1.y};
        ring4[k] = gh; ring4[k + 64] = gh;
        float4 p = p0v[k];
        c0 = cvt2(p.x, p.y);
        c1 = cvt2(p.z, p.w);
        q0[k] = (h4){c0.x, c0.y, c1.x, c1.y};
        p = p1v[k];
        c0 = cvt2(p.x, p.y);
        c1 = cvt2(p.z, p.w);
        q1[k] = (h4){c0.x, c0.y, c1.x, c1.y};
    }

    const h8* q0_8 = (const h8*)q0;      // 32 entries, wave-uniform broadcasts
    const h8* q1_8 = (const h8*)q1;

    h4 W = ring4[k];                     // points {2k, 2k+1}
    float a00 = 0.f, a01 = 0.f, a10 = 0.f, a11 = 0.f;

#pragma unroll 4
    for (int hh = 0; hh < 32; ++hh) {    // j = 4*hh .. 4*hh+3
        h4 na = ring4[k + 2 * hh + 1];   // points {2k+4hh+2, +3}
        h4 nb = ring4[k + 2 * hh + 2];   // points {2k+4hh+4, +5}
        h8 P0 = q0_8[hh];                // pred0 points {4hh..4hh+3}
        h8 P1 = q1_8[hh];

        h2 Wl = lo2(W), Wh = hi2(W), Al = lo2(na), Ah = hi2(na), Bl = lo2(nb);
        h2 p0a = __builtin_shufflevector(P0, P0, 0, 1);
        h2 p0b = __builtin_shufflevector(P0, P0, 2, 3);
        h2 p0c = __builtin_shufflevector(P0, P0, 4, 5);
        h2 p0d = __builtin_shufflevector(P0, P0, 6, 7);
        h2 p1a = __builtin_shufflevector(P1, P1, 0, 1);
        h2 p1b = __builtin_shufflevector(P1, P1, 2, 3);
        h2 p1c = __builtin_shufflevector(P1, P1, 4, 5);
        h2 p1d = __builtin_shufflevector(P1, P1, 6, 7);

        // pred0: shift 2k, then 2k+1
        unit(p0a, Wl, a00); unit(p0b, Wh, a00); unit(p0c, Al, a00); unit(p0d, Ah, a00);
        unit(p0a, Wh, a01); unit(p0b, Al, a01); unit(p0c, Ah, a01); unit(p0d, Bl, a01);
        // pred1
        unit(p1a, Wl, a10); unit(p1b, Wh, a10); unit(p1c, Al, a10); unit(p1d, Ah, a10);
        unit(p1a, Wh, a11); unit(p1b, Al, a11); unit(p1c, Ah, a11); unit(p1d, Bl, a11);

        W = nb;
    }

    // per-pred min over lane's 2 shifts, then over the wave
    float r0 = fminf(a00, a01);
    float r1 = fminf(a10, a11);
#pragma unroll
    for (int m = 32; m > 0; m >>= 1) {
        r0 = fminf(r0, __shfl_xor(r0, m, 64));
        r1 = fminf(r1, __shfl_xor(r1, m, 64));
    }

    __shared__ float bsum[WPB];
    if (k == 0) bsum[w] = r0 + r1;
    __syncthreads();
    if (t == 0) {
        float blockpart = bsum[0] + bsum[1] + bsum[2] + bsum[3];
        // relaxed device-scope atomic; NO fence (R5 lesson: fences -> L2 writeback storm)
        atomicAdd(out, blockpart * (1.0f / (2.0f * BATCH * PNUM)));
    }
}

extern "C" void kernel_launch(void* const* d_in, const int* in_sizes, int n_in,
                              void* d_out, int out_size, void* d_ws, size_t ws_size,
                              hipStream_t stream) {
    const float* pred0 = (const float*)d_in[0];
    const float* pred1 = (const float*)d_in[1];
    const float* gt    = (const float*)d_in[2];
    float* out = (float*)d_out;

    (void)hipMemsetAsync(out, 0, sizeof(float), stream);   // out is 0xAA-poisoned
    match_fused<<<GRID1, 64 * WPB, 0, stream>>>(pred0, pred1, gt, out);
}